// Round 7
// baseline (5144.622 us; speedup 1.0000x reference)
//
#include <hip/hip_runtime.h>
#include <math.h>

#define BATCH 256
#define DIN 512
#define DFEAT 512
#define HSZ 512
#define VOCAB 32000
#define EMB 64
#define SLEN 16
#define NTILE 500          // VOCAB / 64 col-tiles
#define MARGIN 0.0625f
#define MAXCAND 256

typedef __attribute__((ext_vector_type(8))) short bf16x8;
typedef __attribute__((ext_vector_type(4))) float f32x4;

__device__ inline unsigned bf16_rne(float x) {
    union { float f; unsigned u; } u; u.f = x;
    unsigned r = u.u + 0x7fff + ((u.u >> 16) & 1);
    return r >> 16;
}

// ---------- fp32 SMEM GEMM (prologue): C = A @ W^T (+bias) ----------
template<int BM, int BN, int BK, int TM, int TN>
__global__ __launch_bounds__(256) void gemm_atb(
    const float* __restrict__ A,
    const float* __restrict__ W,
    const float* __restrict__ bias,
    float* __restrict__ C, long long ldc,
    int M, int N, int K)
{
    __shared__ float As[BK][BM + 4];
    __shared__ float Bs[BK][BN + 4];
    constexpr int THREADS = (BM / TM) * (BN / TN);
    const int tid = threadIdx.x;
    const int tx = tid % (BN / TN);
    const int ty = tid / (BN / TN);
    const int row0 = blockIdx.y * BM;
    const int col0 = blockIdx.x * BN;
    float acc[TM][TN] = {};
    for (int k0 = 0; k0 < K; k0 += BK) {
        for (int i = tid; i < BM * BK; i += THREADS) {
            int m = i / BK, k = i % BK;
            As[k][m] = A[(long long)(row0 + m) * K + k0 + k];
        }
        for (int i = tid; i < BN * BK; i += THREADS) {
            int n = i / BK, k = i % BK;
            Bs[k][n] = W[(long long)(col0 + n) * K + k0 + k];
        }
        __syncthreads();
        #pragma unroll
        for (int kk = 0; kk < BK; ++kk) {
            float a[TM], b[TN];
            #pragma unroll
            for (int i = 0; i < TM; ++i) a[i] = As[kk][ty * TM + i];
            #pragma unroll
            for (int j = 0; j < TN; ++j) b[j] = Bs[kk][tx * TN + j];
            #pragma unroll
            for (int i = 0; i < TM; ++i)
                #pragma unroll
                for (int j = 0; j < TN; ++j)
                    acc[i][j] = fmaf(a[i], b[j], acc[i][j]);
        }
        __syncthreads();
    }
    #pragma unroll
    for (int i = 0; i < TM; ++i) {
        long long m = row0 + ty * TM + i;
        float* crow = C + m * ldc;
        #pragma unroll
        for (int j = 0; j < TN; ++j) {
            int n = col0 + tx * TN + j;
            float v = acc[i][j];
            if (bias) v += bias[n];
            crow[n] = v;
        }
    }
}

// ---------- fused prologue: Wb cast, Wcat2/bcat2 build (interleaved j*4+comp) ----------
__global__ void prep_kernel(const float* __restrict__ out_W, ushort* __restrict__ Wb,
                            const float* __restrict__ W_ih, const float* __restrict__ W_hh,
                            const float* __restrict__ b_ih, const float* __restrict__ b_hh,
                            float* __restrict__ Wcat2, float* __restrict__ bcat2)
{
    const int stride = gridDim.x * 256;
    const int t0 = blockIdx.x * 256 + threadIdx.x;
    for (int i = t0; i < VOCAB * HSZ / 4; i += stride) {
        const float4 v = ((const float4*)out_W)[i];
        ushort4 o;
        o.x = (ushort)bf16_rne(v.x); o.y = (ushort)bf16_rne(v.y);
        o.z = (ushort)bf16_rne(v.z); o.w = (ushort)bf16_rne(v.w);
        ((ushort4*)Wb)[i] = o;
    }
    for (long long i = t0; i < 2048LL * 576; i += stride) {
        int g = (int)(i / 576), k = (int)(i % 576);
        int j = g >> 2, comp = g & 3;
        float v;
        if (comp == 0)      v = (k < 64) ? W_ih[j * 64 + k]          : W_hh[(long long)j * 512 + k - 64];
        else if (comp == 1) v = (k < 64) ? W_ih[(512 + j) * 64 + k]  : W_hh[(long long)(512 + j) * 512 + k - 64];
        else if (comp == 2) v = (k < 64) ? W_ih[(1024 + j) * 64 + k] : 0.f;
        else                v = (k < 64) ? 0.f                        : W_hh[(long long)(1024 + j) * 512 + k - 64];
        Wcat2[i] = v;
    }
    for (int i = t0; i < 2048; i += stride) {
        int j = i >> 2, comp = i & 3;
        float bv = (comp == 0) ? b_ih[j] + b_hh[j]
                 : (comp == 1) ? b_ih[512 + j] + b_hh[512 + j]
                 : (comp == 2) ? b_ih[1024 + j] : b_hh[1024 + j];
        bcat2[i] = bv;
    }
}

// ---------- AG: [argmax(t-1) +] gcat GEMM + GRU gates. 256 blocks x 256 thr ----------
// Ar/Aw are h-only [256][512]. e-part is sourced from sos (FIRST) or emb[sym] (else).
template<bool FIRST>
__global__ __launch_bounds__(256) void ag_kernel(
    const float* __restrict__ Ar, float* __restrict__ Aw,
    const float* __restrict__ Wcat2, const float* __restrict__ bcat2,
    ushort* __restrict__ hbf,
    const float* __restrict__ tmaxv, const float* __restrict__ lprev,
    const float* __restrict__ out_W, const float* __restrict__ out_b,
    const float* __restrict__ emb, const float* __restrict__ sos,
    float* __restrict__ seq, int tprev)
{
    __shared__ __align__(16) char smem[26624];
    __shared__ int sh_sym[32];
    __shared__ int sh_cr[MAXCAND];
    __shared__ int sh_cc[MAXCAND];
    __shared__ float sh_cv[MAXCAND];
    __shared__ int sh_cn;
    const int tid = threadIdx.x;
    const int lane = tid & 63, wave = tid >> 6;
    const int blk = blockIdx.x;
    const int ty = blk >> 5;            // batch group (32 rows)
    const int tx = blk & 31;            // col group (16 j x 4 comps)

    if (!FIRST) {
        // ---- A-part: argmax of logits(tprev) for rows ty*32..+31 (redundant across tx) ----
        if (tid == 0) sh_cn = 0;
        __syncthreads();
        for (int rr = 0; rr < 8; ++rr) {
            int lrow = wave * 8 + rr;
            int grow = ty * 32 + lrow;
            const float* trow = tmaxv + (long long)grow * 512;
            float m = -INFINITY;
            for (int i = lane; i < NTILE; i += 64) m = fmaxf(m, trow[i]);
            #pragma unroll
            for (int d = 32; d; d >>= 1) m = fmaxf(m, __shfl_xor(m, d, 64));
            const float thr = m - MARGIN;
            const float* row = lprev + (long long)grow * (SLEN * (long long)VOCAB);
            for (int i = lane; i < NTILE; i += 64) {
                if (trow[i] >= thr) {
                    for (int c2 = 0; c2 < 64; ++c2) {
                        int c = i * 64 + c2;
                        float v = row[c];
                        if (v >= thr) {
                            int s = atomicAdd(&sh_cn, 1);
                            if (s < MAXCAND) { sh_cr[s] = lrow; sh_cc[s] = c; }
                        }
                    }
                }
            }
        }
        __syncthreads();
        int nc = min(sh_cn, MAXCAND);
        for (int ci = wave; ci < nc; ci += 4) {
            int cc = sh_cc[ci];
            const float* hrow = Ar + (long long)(ty * 32 + sh_cr[ci]) * 512;
            const float* wrow = out_W + (long long)cc * 512;
            float s = 0.f;
            for (int k = lane; k < 512; k += 64) s = fmaf(hrow[k], wrow[k], s);
            #pragma unroll
            for (int off = 32; off; off >>= 1) s += __shfl_down(s, off, 64);
            if (lane == 0) sh_cv[ci] = s + out_b[cc];
        }
        __syncthreads();
        if (tid < 32) {
            float bv = -INFINITY; int sym = 0x7fffffff;
            for (int ci = 0; ci < nc; ++ci) {
                if (sh_cr[ci] == tid) {
                    float v = sh_cv[ci]; int c = sh_cc[ci];
                    if (v > bv || (v == bv && c < sym)) { bv = v; sym = c; }
                }
            }
            sh_sym[tid] = sym;
            seq[(ty * 32 + tid) * SLEN + tprev] = (float)sym;
        }
        __syncthreads();
    }

    // ---- G-part: gcat tile GEMM + gates (same math as validated round-6 kernel) ----
    float* As = (float*)smem;                    // [64][34]
    float* Bs = (float*)(smem + 8704);           // [64][68]
    const int tyt = tid >> 4;
    const int txt = tid & 15;
    float acc[2][4] = {};
    for (int k0 = 0; k0 < 576; k0 += 64) {
        for (int i = tid; i < 32 * 64; i += 256) {
            int m = i >> 6, k = i & 63;
            int kc = k0 + k;
            float v;
            if (kc < 64) v = FIRST ? sos[kc] : emb[(long long)sh_sym[m] * EMB + kc];
            else         v = Ar[(long long)(ty * 32 + m) * 512 + kc - 64];
            As[k * 34 + m] = v;
        }
        for (int i = tid; i < 64 * 64; i += 256) {
            int n = i >> 6, k = i & 63;
            Bs[k * 68 + n] = Wcat2[(long long)(tx * 64 + n) * 576 + k0 + k];
        }
        __syncthreads();
        #pragma unroll 8
        for (int kk = 0; kk < 64; ++kk) {
            const float2 a = *(const float2*)&As[kk * 34 + tyt * 2];
            const float4 b = *(const float4*)&Bs[kk * 68 + txt * 4];
            acc[0][0] = fmaf(a.x, b.x, acc[0][0]);
            acc[0][1] = fmaf(a.x, b.y, acc[0][1]);
            acc[0][2] = fmaf(a.x, b.z, acc[0][2]);
            acc[0][3] = fmaf(a.x, b.w, acc[0][3]);
            acc[1][0] = fmaf(a.y, b.x, acc[1][0]);
            acc[1][1] = fmaf(a.y, b.y, acc[1][1]);
            acc[1][2] = fmaf(a.y, b.z, acc[1][2]);
            acc[1][3] = fmaf(a.y, b.w, acc[1][3]);
        }
        __syncthreads();
    }
    float* gt = (float*)smem;            // [32][64] reuse
    #pragma unroll
    for (int i = 0; i < 2; ++i)
        #pragma unroll
        for (int j = 0; j < 4; ++j)
            gt[(tyt * 2 + i) * 64 + txt * 4 + j] = acc[i][j];
    __syncthreads();
    for (int p = tid; p < 512; p += 256) {
        int bl = p >> 4, jl = p & 15;
        int jg = tx * 16 + jl;
        float gr  = gt[bl * 64 + jl * 4 + 0] + bcat2[jg * 4 + 0];
        float gz  = gt[bl * 64 + jl * 4 + 1] + bcat2[jg * 4 + 1];
        float gni = gt[bl * 64 + jl * 4 + 2] + bcat2[jg * 4 + 2];
        float gnh = gt[bl * 64 + jl * 4 + 3] + bcat2[jg * 4 + 3];
        float r = 1.0f / (1.0f + expf(-gr));
        float z = 1.0f / (1.0f + expf(-gz));
        float n = tanhf(gni + r * gnh);
        long long bglob = ty * 32 + bl;
        float hold = Ar[bglob * 512 + jg];
        float h = (1.0f - z) * n + z * hold;
        Aw[bglob * 512 + jg] = h;
        hbf[bglob * 512 + jg] = (ushort)bf16_rne(h);
    }
}

// ---------- L: logits MFMA, BM=256 x BN=64, 500 blocks (validated round 6) ----------
__global__ __launch_bounds__(256) void logits_bm256_kernel(
    const ushort* __restrict__ hbf,
    const ushort* __restrict__ Wb,
    const float* __restrict__ out_b,
    float* __restrict__ lbase, float* __restrict__ tmaxv)
{
    __shared__ __align__(16) char As[32768];
    __shared__ __align__(16) char Bs[8192];
    __shared__ float s_mv[256];
    const int tid = threadIdx.x;
    const int lane = tid & 63;
    const int wave = tid >> 6;
    const int jx = blockIdx.x;
    const int col0 = jx * 64;

    f32x4 acc[4][4] = {};
    const int srow = tid >> 3;
    const int sch = tid & 7;

    for (int k0 = 0; k0 < 512; k0 += 64) {
        #pragma unroll
        for (int ra = 0; ra < 8; ++ra) {
            int row = ra * 32 + srow;
            const char* g = (const char*)(hbf + (long long)row * 512 + k0) + ((sch ^ (row & 7)) * 16);
            __builtin_amdgcn_global_load_lds(
                (const __attribute__((address_space(1))) void*)g,
                (__attribute__((address_space(3))) void*)(As + row * 128 + sch * 16), 16, 0, 0);
        }
        #pragma unroll
        for (int rb = 0; rb < 2; ++rb) {
            int row = rb * 32 + srow;
            const char* g = (const char*)(Wb + (long long)(col0 + row) * 512 + k0) + ((sch ^ (row & 7)) * 16);
            __builtin_amdgcn_global_load_lds(
                (const __attribute__((address_space(1))) void*)g,
                (__attribute__((address_space(3))) void*)(Bs + row * 128 + sch * 16), 16, 0, 0);
        }
        __syncthreads();
        #pragma unroll
        for (int k32 = 0; k32 < 64; k32 += 32) {
            bf16x8 af[4], bfr[4];
            #pragma unroll
            for (int f = 0; f < 4; ++f) {
                int rA = wave * 64 + f * 16 + (lane & 15);
                int byteA = (rA * 128 + (k32 + ((lane >> 4) << 3)) * 2) ^ ((rA & 7) << 4);
                af[f] = *(const bf16x8*)&As[byteA];
            }
            #pragma unroll
            for (int j = 0; j < 4; ++j) {
                int rB = j * 16 + (lane & 15);
                int byteB = (rB * 128 + (k32 + ((lane >> 4) << 3)) * 2) ^ ((rB & 7) << 4);
                bfr[j] = *(const bf16x8*)&Bs[byteB];
            }
            #pragma unroll
            for (int f = 0; f < 4; ++f)
                #pragma unroll
                for (int j = 0; j < 4; ++j)
                    acc[f][j] = __builtin_amdgcn_mfma_f32_16x16x32_bf16(af[f], bfr[j], acc[f][j], 0, 0, 0);
        }
        __syncthreads();
    }

    #pragma unroll
    for (int f = 0; f < 4; ++f) {
        #pragma unroll
        for (int q = 0; q < 4; ++q) {
            int r_local = wave * 64 + f * 16 + ((lane >> 4) << 2) + q;
            float* crow = lbase + (long long)r_local * (SLEN * (long long)VOCAB);
            float mv = -INFINITY;
            #pragma unroll
            for (int j = 0; j < 4; ++j) {
                int c = col0 + j * 16 + (lane & 15);
                float v = acc[f][j][q] + out_b[c];
                crow[c] = v;
                mv = fmaxf(mv, v);
            }
            #pragma unroll
            for (int m = 1; m < 16; m <<= 1) mv = fmaxf(mv, __shfl_xor(mv, m, 64));
            if ((lane & 15) == 0) s_mv[r_local] = mv;
        }
    }
    __syncthreads();
    tmaxv[(long long)tid * 512 + jx] = s_mv[tid];
}

// ---------- final argmax (t = SLEN-1): seq only ----------
__global__ __launch_bounds__(256) void argmax_final(
    const float* __restrict__ tmaxv, const float* __restrict__ lbase,
    const float* __restrict__ hstate, const float* __restrict__ out_W,
    const float* __restrict__ out_b, float* __restrict__ seq, int t)
{
    __shared__ float s_red[256];
    __shared__ int s_qt[32];
    __shared__ int s_cand[32];
    __shared__ float s_rv[32];
    __shared__ int s_cnt2[2];
    const int b = blockIdx.x;
    const int tid = threadIdx.x;
    const int lane = tid & 63, wave = tid >> 6;
    const float* row = lbase + (long long)b * (SLEN * (long long)VOCAB);

    float v0 = tmaxv[(long long)b * 512 + tid];
    float v1 = (tid + 256 < NTILE) ? tmaxv[(long long)b * 512 + 256 + tid] : -INFINITY;
    s_red[tid] = fmaxf(v0, v1); __syncthreads();
    for (int s = 128; s > 0; s >>= 1) {
        if (tid < s) s_red[tid] = fmaxf(s_red[tid], s_red[tid + s]);
        __syncthreads();
    }
    float M = s_red[0];
    if (tid == 0) { s_cnt2[0] = 0; s_cnt2[1] = 0; }
    __syncthreads();
    if (v0 >= M - MARGIN) {
        int s = atomicAdd(&s_cnt2[0], 1);
        if (s < 32) s_qt[s] = tid;
    }
    if (v1 >= M - MARGIN) {
        int s = atomicAdd(&s_cnt2[0], 1);
        if (s < 32) s_qt[s] = tid + 256;
    }
    __syncthreads();
    int nq = min(s_cnt2[0], 32);
    for (int idx = tid; idx < nq * 64; idx += 256) {
        int c = s_qt[idx >> 6] * 64 + (idx & 63);
        if (row[c] >= M - MARGIN) {
            int s = atomicAdd(&s_cnt2[1], 1);
            if (s < 32) s_cand[s] = c;
        }
    }
    __syncthreads();
    int nc = min(s_cnt2[1], 32);
    const float* hrow = hstate + (long long)b * 512;
    for (int ci = wave; ci < nc; ci += 4) {
        int vv = s_cand[ci];
        const float* wrow = out_W + (long long)vv * 512;
        float s = 0.f;
        for (int k = lane; k < 512; k += 64) s = fmaf(hrow[k], wrow[k], s);
        for (int off = 32; off > 0; off >>= 1) s += __shfl_down(s, off, 64);
        if (lane == 0) s_rv[ci] = s + out_b[vv];
    }
    __syncthreads();
    if (tid == 0) {
        float bv = -INFINITY; int sym = 0x7fffffff;
        for (int ci = 0; ci < nc; ++ci) {
            float xx = s_rv[ci]; int c = s_cand[ci];
            if (xx > bv || (xx == bv && c < sym)) { bv = xx; sym = c; }
        }
        seq[b * SLEN + t] = (float)sym;
    }
}

extern "C" void kernel_launch(void* const* d_in, const int* in_sizes, int n_in,
                              void* d_out, int out_size, void* d_ws, size_t ws_size,
                              hipStream_t stream) {
    const float* x     = (const float*)d_in[0];
    const float* enc_W = (const float*)d_in[1];
    const float* enc_b = (const float*)d_in[2];
    const float* in_W  = (const float*)d_in[3];
    const float* in_b  = (const float*)d_in[4];
    const float* W_ih  = (const float*)d_in[5];
    const float* W_hh  = (const float*)d_in[6];
    const float* b_ih  = (const float*)d_in[7];
    const float* b_hh  = (const float*)d_in[8];
    const float* out_W = (const float*)d_in[9];
    const float* out_b = (const float*)d_in[10];
    const float* emb   = (const float*)d_in[11];
    const float* sos   = (const float*)d_in[12];

    float* seq    = (float*)d_out;
    float* logits = (float*)d_out + BATCH * SLEN;

    char* p = (char*)d_ws;
    ushort* Wb    = (ushort*)p;  p += (size_t)VOCAB * HSZ * 2;
    float* Wcat2  = (float*)p;   p += (size_t)2048 * 576 * 4;
    float* bcat2  = (float*)p;   p += 2048 * 4;
    float* AcatA  = (float*)p;   p += (size_t)BATCH * HSZ * 4;
    float* AcatB  = (float*)p;   p += (size_t)BATCH * HSZ * 4;
    ushort* hbf   = (ushort*)p;  p += (size_t)BATCH * HSZ * 2;
    float* feat   = (float*)p;   p += (size_t)BATCH * DFEAT * 4;
    float* tmaxv  = (float*)p;   p += (size_t)BATCH * 512 * 4;

    // prologue: weights prep + encoder -> input_layer -> h0 (into AcatA)
    prep_kernel<<<1024, 256, 0, stream>>>(out_W, Wb, W_ih, W_hh, b_ih, b_hh, Wcat2, bcat2);
    gemm_atb<64, 64, 32, 4, 4><<<dim3(DFEAT / 64, BATCH / 64), 256, 0, stream>>>(
        x, enc_W, enc_b, feat, DFEAT, BATCH, DFEAT, DIN);
    gemm_atb<64, 64, 32, 4, 4><<<dim3(HSZ / 64, BATCH / 64), 256, 0, stream>>>(
        feat, in_W, in_b, AcatA, HSZ, BATCH, HSZ, DFEAT);

    for (int t = 0; t < SLEN; ++t) {
        const float* Ar = (t & 1) ? AcatB : AcatA;
        float*       Aw = (t & 1) ? AcatA : AcatB;
        float* lbase = logits + (long long)t * VOCAB;
        if (t == 0) {
            ag_kernel<true><<<256, 256, 0, stream>>>(
                Ar, Aw, Wcat2, bcat2, hbf, tmaxv, logits, out_W, out_b, emb, sos, seq, 0);
        } else {
            ag_kernel<false><<<256, 256, 0, stream>>>(
                Ar, Aw, Wcat2, bcat2, hbf, tmaxv, logits + (long long)(t - 1) * VOCAB,
                out_W, out_b, emb, sos, seq, t - 1);
        }
        logits_bm256_kernel<<<NTILE, 256, 0, stream>>>(hbf, Wb, out_b, lbase, tmaxv);
    }
    // final argmax: h state after step 15 is in AcatA (15 odd -> Aw = AcatA)
    argmax_final<<<BATCH, 256, 0, stream>>>(
        tmaxv, logits + (long long)(SLEN - 1) * VOCAB, AcatA, out_W, out_b, seq, SLEN - 1);
}

// Round 9
// 2637.248 us; speedup vs baseline: 1.9508x; 1.9508x over previous
//
#include <hip/hip_runtime.h>
#include <math.h>

#define BATCH 256
#define DIN 512
#define DFEAT 512
#define HSZ 512
#define VOCAB 32000
#define EMB 64
#define SLEN 16
#define NTILE 500          // VOCAB / 64 col-tiles
#define MARGIN 0.0625f
#define MAXPAIR 384
#define MAXCAND 384

typedef __attribute__((ext_vector_type(8))) short bf16x8;
typedef __attribute__((ext_vector_type(4))) float f32x4;

__device__ inline unsigned bf16_rne(float x) {
    union { float f; unsigned u; } u; u.f = x;
    unsigned r = u.u + 0x7fff + ((u.u >> 16) & 1);
    return r >> 16;
}

// ---------- fp32 SMEM GEMM (prologue): C = A @ W^T (+bias) ----------
template<int BM, int BN, int BK, int TM, int TN>
__global__ __launch_bounds__(256) void gemm_atb(
    const float* __restrict__ A,
    const float* __restrict__ W,
    const float* __restrict__ bias,
    float* __restrict__ C, long long ldc,
    int M, int N, int K)
{
    __shared__ float As[BK][BM + 4];
    __shared__ float Bs[BK][BN + 4];
    constexpr int THREADS = (BM / TM) * (BN / TN);
    const int tid = threadIdx.x;
    const int tx = tid % (BN / TN);
    const int ty = tid / (BN / TN);
    const int row0 = blockIdx.y * BM;
    const int col0 = blockIdx.x * BN;
    float acc[TM][TN] = {};
    for (int k0 = 0; k0 < K; k0 += BK) {
        for (int i = tid; i < BM * BK; i += THREADS) {
            int m = i / BK, k = i % BK;
            As[k][m] = A[(long long)(row0 + m) * K + k0 + k];
        }
        for (int i = tid; i < BN * BK; i += THREADS) {
            int n = i / BK, k = i % BK;
            Bs[k][n] = W[(long long)(col0 + n) * K + k0 + k];
        }
        __syncthreads();
        #pragma unroll
        for (int kk = 0; kk < BK; ++kk) {
            float a[TM], b[TN];
            #pragma unroll
            for (int i = 0; i < TM; ++i) a[i] = As[kk][ty * TM + i];
            #pragma unroll
            for (int j = 0; j < TN; ++j) b[j] = Bs[kk][tx * TN + j];
            #pragma unroll
            for (int i = 0; i < TM; ++i)
                #pragma unroll
                for (int j = 0; j < TN; ++j)
                    acc[i][j] = fmaf(a[i], b[j], acc[i][j]);
        }
        __syncthreads();
    }
    #pragma unroll
    for (int i = 0; i < TM; ++i) {
        long long m = row0 + ty * TM + i;
        float* crow = C + m * ldc;
        #pragma unroll
        for (int j = 0; j < TN; ++j) {
            int n = col0 + tx * TN + j;
            float v = acc[i][j];
            if (bias) v += bias[n];
            crow[n] = v;
        }
    }
}

// ---------- fused prologue: Wb cast, Wcat2/bcat2 build (interleaved j*4+comp) ----------
__global__ void prep_kernel(const float* __restrict__ out_W, ushort* __restrict__ Wb,
                            const float* __restrict__ W_ih, const float* __restrict__ W_hh,
                            const float* __restrict__ b_ih, const float* __restrict__ b_hh,
                            float* __restrict__ Wcat2, float* __restrict__ bcat2)
{
    const int stride = gridDim.x * 256;
    const int t0 = blockIdx.x * 256 + threadIdx.x;
    for (int i = t0; i < VOCAB * HSZ / 4; i += stride) {
        const float4 v = ((const float4*)out_W)[i];
        ushort4 o;
        o.x = (ushort)bf16_rne(v.x); o.y = (ushort)bf16_rne(v.y);
        o.z = (ushort)bf16_rne(v.z); o.w = (ushort)bf16_rne(v.w);
        ((ushort4*)Wb)[i] = o;
    }
    for (long long i = t0; i < 2048LL * 576; i += stride) {
        int g = (int)(i / 576), k = (int)(i % 576);
        int j = g >> 2, comp = g & 3;
        float v;
        if (comp == 0)      v = (k < 64) ? W_ih[j * 64 + k]          : W_hh[(long long)j * 512 + k - 64];
        else if (comp == 1) v = (k < 64) ? W_ih[(512 + j) * 64 + k]  : W_hh[(long long)(512 + j) * 512 + k - 64];
        else if (comp == 2) v = (k < 64) ? W_ih[(1024 + j) * 64 + k] : 0.f;
        else                v = (k < 64) ? 0.f                        : W_hh[(long long)(1024 + j) * 512 + k - 64];
        Wcat2[i] = v;
    }
    for (int i = t0; i < 2048; i += stride) {
        int j = i >> 2, comp = i & 3;
        float bv = (comp == 0) ? b_ih[j] + b_hh[j]
                 : (comp == 1) ? b_ih[512 + j] + b_hh[512 + j]
                 : (comp == 2) ? b_ih[1024 + j] : b_hh[1024 + j];
        bcat2[i] = bv;
    }
}

// ---------- AG: [parallel argmax(t-1) +] gcat GEMM + GRU gates. 256 blocks ----------
template<bool FIRST>
__global__ __launch_bounds__(256) void ag_kernel(
    const float* __restrict__ Ar, float* __restrict__ Aw,
    const float* __restrict__ Wcat2, const float* __restrict__ bcat2,
    ushort* __restrict__ hbf,
    const float* __restrict__ tmaxv, const float* __restrict__ lprev,
    const float* __restrict__ out_W, const float* __restrict__ out_b,
    const float* __restrict__ emb, const float* __restrict__ sos,
    float* __restrict__ seq, int tprev)
{
    __shared__ __align__(16) char smem[26624];
    __shared__ int sh_sym[32];
    __shared__ float sh_thr[32];
    __shared__ int sh_pr[MAXPAIR];
    __shared__ int sh_pt[MAXPAIR];
    __shared__ int sh_cr[MAXCAND];
    __shared__ int sh_cc[MAXCAND];
    __shared__ float sh_cv[MAXCAND];
    __shared__ int sh_np;
    __shared__ int sh_cn;
    const int tid = threadIdx.x;
    const int lane = tid & 63, wave = tid >> 6;
    const int blk = blockIdx.x;
    const int ty = blk >> 5;            // batch group (32 rows)
    const int tx = blk & 31;            // col group (16 j x 4 comps)

    if (!FIRST) {
        // ---- A-part (parallel): argmax of logits(tprev) for rows ty*32..+31 ----
        if (tid == 0) { sh_np = 0; sh_cn = 0; }
        __syncthreads();
        // 1: per-row max over 500 tile-maxes; collect qualifying tiles in parallel
        for (int rr = 0; rr < 8; ++rr) {
            int lrow = wave * 8 + rr;
            int grow = ty * 32 + lrow;
            const float* trow = tmaxv + (long long)grow * 512;
            float tv[8];
            float m = -INFINITY;
            #pragma unroll
            for (int s = 0; s < 8; ++s) {
                int i = lane + (s << 6);
                tv[s] = (i < NTILE) ? trow[i] : -INFINITY;
                m = fmaxf(m, tv[s]);
            }
            #pragma unroll
            for (int d = 32; d; d >>= 1) m = fmaxf(m, __shfl_xor(m, d, 64));
            const float thr = m - MARGIN;
            if (lane == 0) sh_thr[lrow] = thr;
            #pragma unroll
            for (int s = 0; s < 8; ++s) {
                int i = lane + (s << 6);
                if (i < NTILE && tv[s] >= thr) {
                    int sl = atomicAdd(&sh_np, 1);
                    if (sl < MAXPAIR) { sh_pr[sl] = lrow; sh_pt[sl] = i; }
                }
            }
        }
        __syncthreads();
        int np = min(sh_np, MAXPAIR);
        // 2: scan qualifying tiles — one wave per tile, 64 lanes read 64 cols at once
        for (int pi = wave; pi < np; pi += 4) {
            int lrow = sh_pr[pi], tile = sh_pt[pi];
            float thr = sh_thr[lrow];
            const float* row = lprev + (long long)(ty * 32 + lrow) * (SLEN * (long long)VOCAB);
            float v = row[tile * 64 + lane];
            if (v >= thr) {
                int sl = atomicAdd(&sh_cn, 1);
                if (sl < MAXCAND) { sh_cr[sl] = lrow; sh_cc[sl] = tile * 64 + lane; }
            }
        }
        __syncthreads();
        int nc = min(sh_cn, MAXCAND);
        // 3: exact fp32 refine — one wave per candidate
        for (int ci = wave; ci < nc; ci += 4) {
            int cc = sh_cc[ci];
            const float* hrow = Ar + (long long)(ty * 32 + sh_cr[ci]) * 512;
            const float* wrow = out_W + (long long)cc * 512;
            float s = 0.f;
            for (int k = lane; k < 512; k += 64) s = fmaf(hrow[k], wrow[k], s);
            #pragma unroll
            for (int off = 32; off; off >>= 1) s += __shfl_down(s, off, 64);
            if (lane == 0) sh_cv[ci] = s + out_b[cc];
        }
        __syncthreads();
        // 4: per-row select (defensive: fall back to 0 if a row lost all candidates)
        if (tid < 32) {
            float bv = -INFINITY; int sym = 0x7fffffff;
            for (int ci = 0; ci < nc; ++ci) {
                if (sh_cr[ci] == tid) {
                    float v = sh_cv[ci]; int c = sh_cc[ci];
                    if (v > bv || (v == bv && c < sym)) { bv = v; sym = c; }
                }
            }
            if (sym < 0 || sym >= VOCAB) sym = 0;   // crash-proofing (should never trigger)
            sh_sym[tid] = sym;
            seq[(ty * 32 + tid) * SLEN + tprev] = (float)sym;
        }
        __syncthreads();
    }

    // ---- G-part: gcat tile GEMM + gates (validated math, rounds 5-7) ----
    float* As = (float*)smem;                    // [64][34]
    float* Bs = (float*)(smem + 8704);           // [64][68]
    const int tyt = tid >> 4;
    const int txt = tid & 15;
    float acc[2][4] = {};
    for (int k0 = 0; k0 < 576; k0 += 64) {
        for (int i = tid; i < 32 * 64; i += 256) {
            int m = i >> 6, k = i & 63;
            int kc = k0 + k;
            float v;
            if (kc < 64) v = FIRST ? sos[kc] : emb[(long long)sh_sym[m] * EMB + kc];
            else         v = Ar[(long long)(ty * 32 + m) * 512 + kc - 64];
            As[k * 34 + m] = v;
        }
        for (int i = tid; i < 64 * 64; i += 256) {
            int n = i >> 6, k = i & 63;
            Bs[k * 68 + n] = Wcat2[(long long)(tx * 64 + n) * 576 + k0 + k];
        }
        __syncthreads();
        #pragma unroll 8
        for (int kk = 0; kk < 64; ++kk) {
            const float2 a = *(const float2*)&As[kk * 34 + tyt * 2];
            const float4 b = *(const float4*)&Bs[kk * 68 + txt * 4];
            acc[0][0] = fmaf(a.x, b.x, acc[0][0]);
            acc[0][1] = fmaf(a.x, b.y, acc[0][1]);
            acc[0][2] = fmaf(a.x, b.z, acc[0][2]);
            acc[0][3] = fmaf(a.x, b.w, acc[0][3]);
            acc[1][0] = fmaf(a.y, b.x, acc[1][0]);
            acc[1][1] = fmaf(a.y, b.y, acc[1][1]);
            acc[1][2] = fmaf(a.y, b.z, acc[1][2]);
            acc[1][3] = fmaf(a.y, b.w, acc[1][3]);
        }
        __syncthreads();
    }
    float* gt = (float*)smem;            // [32][64] reuse
    #pragma unroll
    for (int i = 0; i < 2; ++i)
        #pragma unroll
        for (int j = 0; j < 4; ++j)
            gt[(tyt * 2 + i) * 64 + txt * 4 + j] = acc[i][j];
    __syncthreads();
    for (int p = tid; p < 512; p += 256) {
        int bl = p >> 4, jl = p & 15;
        int jg = tx * 16 + jl;
        float gr  = gt[bl * 64 + jl * 4 + 0] + bcat2[jg * 4 + 0];
        float gz  = gt[bl * 64 + jl * 4 + 1] + bcat2[jg * 4 + 1];
        float gni = gt[bl * 64 + jl * 4 + 2] + bcat2[jg * 4 + 2];
        float gnh = gt[bl * 64 + jl * 4 + 3] + bcat2[jg * 4 + 3];
        float r = 1.0f / (1.0f + expf(-gr));
        float z = 1.0f / (1.0f + expf(-gz));
        float n = tanhf(gni + r * gnh);
        long long bglob = ty * 32 + bl;
        float hold = Ar[bglob * 512 + jg];
        float h = (1.0f - z) * n + z * hold;
        Aw[bglob * 512 + jg] = h;
        hbf[bglob * 512 + jg] = (ushort)bf16_rne(h);
    }
}

// ---------- L: logits MFMA, BM=256 x BN=64, 500 blocks (validated round 6) ----------
__global__ __launch_bounds__(256) void logits_bm256_kernel(
    const ushort* __restrict__ hbf,
    const ushort* __restrict__ Wb,
    const float* __restrict__ out_b,
    float* __restrict__ lbase, float* __restrict__ tmaxv)
{
    __shared__ __align__(16) char As[32768];
    __shared__ __align__(16) char Bs[8192];
    __shared__ float s_mv[256];
    const int tid = threadIdx.x;
    const int lane = tid & 63;
    const int wave = tid >> 6;
    const int jx = blockIdx.x;
    const int col0 = jx * 64;

    f32x4 acc[4][4] = {};
    const int srow = tid >> 3;
    const int sch = tid & 7;

    for (int k0 = 0; k0 < 512; k0 += 64) {
        #pragma unroll
        for (int ra = 0; ra < 8; ++ra) {
            int row = ra * 32 + srow;
            const char* g = (const char*)(hbf + (long long)row * 512 + k0) + ((sch ^ (row & 7)) * 16);
            __builtin_amdgcn_global_load_lds(
                (const __attribute__((address_space(1))) void*)g,
                (__attribute__((address_space(3))) void*)(As + row * 128 + sch * 16), 16, 0, 0);
        }
        #pragma unroll
        for (int rb = 0; rb < 2; ++rb) {
            int row = rb * 32 + srow;
            const char* g = (const char*)(Wb + (long long)(col0 + row) * 512 + k0) + ((sch ^ (row & 7)) * 16);
            __builtin_amdgcn_global_load_lds(
                (const __attribute__((address_space(1))) void*)g,
                (__attribute__((address_space(3))) void*)(Bs + row * 128 + sch * 16), 16, 0, 0);
        }
        __syncthreads();
        #pragma unroll
        for (int k32 = 0; k32 < 64; k32 += 32) {
            bf16x8 af[4], bfr[4];
            #pragma unroll
            for (int f = 0; f < 4; ++f) {
                int rA = wave * 64 + f * 16 + (lane & 15);
                int byteA = (rA * 128 + (k32 + ((lane >> 4) << 3)) * 2) ^ ((rA & 7) << 4);
                af[f] = *(const bf16x8*)&As[byteA];
            }
            #pragma unroll
            for (int j = 0; j < 4; ++j) {
                int rB = j * 16 + (lane & 15);
                int byteB = (rB * 128 + (k32 + ((lane >> 4) << 3)) * 2) ^ ((rB & 7) << 4);
                bfr[j] = *(const bf16x8*)&Bs[byteB];
            }
            #pragma unroll
            for (int f = 0; f < 4; ++f)
                #pragma unroll
                for (int j = 0; j < 4; ++j)
                    acc[f][j] = __builtin_amdgcn_mfma_f32_16x16x32_bf16(af[f], bfr[j], acc[f][j], 0, 0, 0);
        }
        __syncthreads();
    }

    #pragma unroll
    for (int f = 0; f < 4; ++f) {
        #pragma unroll
        for (int q = 0; q < 4; ++q) {
            int r_local = wave * 64 + f * 16 + ((lane >> 4) << 2) + q;
            float* crow = lbase + (long long)r_local * (SLEN * (long long)VOCAB);
            float mv = -INFINITY;
            #pragma unroll
            for (int j = 0; j < 4; ++j) {
                int c = col0 + j * 16 + (lane & 15);
                float v = acc[f][j][q] + out_b[c];
                crow[c] = v;
                mv = fmaxf(mv, v);
            }
            #pragma unroll
            for (int m = 1; m < 16; m <<= 1) mv = fmaxf(mv, __shfl_xor(mv, m, 64));
            if ((lane & 15) == 0) s_mv[r_local] = mv;
        }
    }
    __syncthreads();
    tmaxv[(long long)tid * 512 + jx] = s_mv[tid];
}

// ---------- final argmax (t = SLEN-1): seq only ----------
__global__ __launch_bounds__(256) void argmax_final(
    const float* __restrict__ tmaxv, const float* __restrict__ lbase,
    const float* __restrict__ hstate, const float* __restrict__ out_W,
    const float* __restrict__ out_b, float* __restrict__ seq, int t)
{
    __shared__ float s_red[256];
    __shared__ int s_qt[64];
    __shared__ int s_cand[64];
    __shared__ float s_rv[64];
    __shared__ int s_cnt2[2];
    const int b = blockIdx.x;
    const int tid = threadIdx.x;
    const int lane = tid & 63, wave = tid >> 6;
    const float* row = lbase + (long long)b * (SLEN * (long long)VOCAB);

    float v0 = tmaxv[(long long)b * 512 + tid];
    float v1 = (tid + 256 < NTILE) ? tmaxv[(long long)b * 512 + 256 + tid] : -INFINITY;
    s_red[tid] = fmaxf(v0, v1); __syncthreads();
    for (int s = 128; s > 0; s >>= 1) {
        if (tid < s) s_red[tid] = fmaxf(s_red[tid], s_red[tid + s]);
        __syncthreads();
    }
    float M = s_red[0];
    if (tid == 0) { s_cnt2[0] = 0; s_cnt2[1] = 0; }
    __syncthreads();
    if (v0 >= M - MARGIN) {
        int s = atomicAdd(&s_cnt2[0], 1);
        if (s < 64) s_qt[s] = tid;
    }
    if (v1 >= M - MARGIN) {
        int s = atomicAdd(&s_cnt2[0], 1);
        if (s < 64) s_qt[s] = tid + 256;
    }
    __syncthreads();
    int nq = min(s_cnt2[0], 64);
    for (int idx = tid; idx < nq * 64; idx += 256) {
        int c = s_qt[idx >> 6] * 64 + (idx & 63);
        if (row[c] >= M - MARGIN) {
            int s = atomicAdd(&s_cnt2[1], 1);
            if (s < 64) s_cand[s] = c;
        }
    }
    __syncthreads();
    int nc = min(s_cnt2[1], 64);
    const float* hrow = hstate + (long long)b * 512;
    for (int ci = wave; ci < nc; ci += 4) {
        int vv = s_cand[ci];
        const float* wrow = out_W + (long long)vv * 512;
        float s = 0.f;
        for (int k = lane; k < 512; k += 64) s = fmaf(hrow[k], wrow[k], s);
        for (int off = 32; off > 0; off >>= 1) s += __shfl_down(s, off, 64);
        if (lane == 0) s_rv[ci] = s + out_b[vv];
    }
    __syncthreads();
    if (tid == 0) {
        float bv = -INFINITY; int sym = 0x7fffffff;
        for (int ci = 0; ci < nc; ++ci) {
            float xx = s_rv[ci]; int c = s_cand[ci];
            if (xx > bv || (xx == bv && c < sym)) { bv = xx; sym = c; }
        }
        if (sym < 0 || sym >= VOCAB) sym = 0;
        seq[b * SLEN + t] = (float)sym;
    }
}

extern "C" void kernel_launch(void* const* d_in, const int* in_sizes, int n_in,
                              void* d_out, int out_size, void* d_ws, size_t ws_size,
                              hipStream_t stream) {
    const float* x     = (const float*)d_in[0];
    const float* enc_W = (const float*)d_in[1];
    const float* enc_b = (const float*)d_in[2];
    const float* in_W  = (const float*)d_in[3];
    const float* in_b  = (const float*)d_in[4];
    const float* W_ih  = (const float*)d_in[5];
    const float* W_hh  = (const float*)d_in[6];
    const float* b_ih  = (const float*)d_in[7];
    const float* b_hh  = (const float*)d_in[8];
    const float* out_W = (const float*)d_in[9];
    const float* out_b = (const float*)d_in[10];
    const float* emb   = (const float*)d_in[11];
    const float* sos   = (const float*)d_in[12];

    float* seq    = (float*)d_out;
    float* logits = (float*)d_out + BATCH * SLEN;

    char* p = (char*)d_ws;
    ushort* Wb    = (ushort*)p;  p += (size_t)VOCAB * HSZ * 2;
    float* Wcat2  = (float*)p;   p += (size_t)2048 * 576 * 4;
    float* bcat2  = (float*)p;   p += 2048 * 4;
    float* AcatA  = (float*)p;   p += (size_t)BATCH * HSZ * 4;
    float* AcatB  = (float*)p;   p += (size_t)BATCH * HSZ * 4;
    ushort* hbf   = (ushort*)p;  p += (size_t)BATCH * HSZ * 2;
    float* feat   = (float*)p;   p += (size_t)BATCH * DFEAT * 4;
    float* tmaxv  = (float*)p;   p += (size_t)BATCH * 512 * 4;

    // prologue: weights prep + encoder -> input_layer -> h0 (into AcatA)
    prep_kernel<<<1024, 256, 0, stream>>>(out_W, Wb, W_ih, W_hh, b_ih, b_hh, Wcat2, bcat2);
    gemm_atb<64, 64, 32, 4, 4><<<dim3(DFEAT / 64, BATCH / 64), 256, 0, stream>>>(
        x, enc_W, enc_b, feat, DFEAT, BATCH, DFEAT, DIN);
    gemm_atb<64, 64, 32, 4, 4><<<dim3(HSZ / 64, BATCH / 64), 256, 0, stream>>>(
        feat, in_W, in_b, AcatA, HSZ, BATCH, HSZ, DFEAT);

    for (int t = 0; t < SLEN; ++t) {
        const float* Ar = (t & 1) ? AcatB : AcatA;
        float*       Aw = (t & 1) ? AcatA : AcatB;
        float* lbase = logits + (long long)t * VOCAB;
        if (t == 0) {
            ag_kernel<true><<<256, 256, 0, stream>>>(
                Ar, Aw, Wcat2, bcat2, hbf, tmaxv, logits, out_W, out_b, emb, sos, seq, 0);
        } else {
            ag_kernel<false><<<256, 256, 0, stream>>>(
                Ar, Aw, Wcat2, bcat2, hbf, tmaxv, logits + (long long)(t - 1) * VOCAB,
                out_W, out_b, emb, sos, seq, t - 1);
        }
        logits_bm256_kernel<<<NTILE, 256, 0, stream>>>(hbf, Wb, out_b, lbase, tmaxv);
    }
    // final argmax: h state after step 15 is in AcatA (15 odd -> Aw = AcatA)
    argmax_final<<<BATCH, 256, 0, stream>>>(
        tmaxv, logits + (long long)(SLEN - 1) * VOCAB, AcatA, out_W, out_b, seq, SLEN - 1);
}

// Round 10
// 1230.317 us; speedup vs baseline: 4.1815x; 2.1436x over previous
//
#include <hip/hip_runtime.h>
#include <math.h>

#define BATCH 256
#define DIN 512
#define DFEAT 512
#define HSZ 512
#define VOCAB 32000
#define EMB 64
#define SLEN 16
#define NTILE 500          // VOCAB / 64 col-tiles
#define MARGIN 0.0625f

typedef __attribute__((ext_vector_type(8))) short bf16x8;
typedef __attribute__((ext_vector_type(4))) float f32x4;

__device__ inline unsigned bf16_rne(float x) {
    union { float f; unsigned u; } u; u.f = x;
    unsigned r = u.u + 0x7fff + ((u.u >> 16) & 1);
    return r >> 16;
}

// ---------- fp32 SMEM GEMM (prologue): C = A @ W^T (+bias) ----------
template<int BM, int BN, int BK, int TM, int TN>
__global__ __launch_bounds__(256) void gemm_atb(
    const float* __restrict__ A,
    const float* __restrict__ W,
    const float* __restrict__ bias,
    float* __restrict__ C, long long ldc,
    int M, int N, int K)
{
    __shared__ float As[BK][BM + 4];
    __shared__ float Bs[BK][BN + 4];
    constexpr int THREADS = (BM / TM) * (BN / TN);
    const int tid = threadIdx.x;
    const int tx = tid % (BN / TN);
    const int ty = tid / (BN / TN);
    const int row0 = blockIdx.y * BM;
    const int col0 = blockIdx.x * BN;
    float acc[TM][TN] = {};
    for (int k0 = 0; k0 < K; k0 += BK) {
        for (int i = tid; i < BM * BK; i += THREADS) {
            int m = i / BK, k = i % BK;
            As[k][m] = A[(long long)(row0 + m) * K + k0 + k];
        }
        for (int i = tid; i < BN * BK; i += THREADS) {
            int n = i / BK, k = i % BK;
            Bs[k][n] = W[(long long)(col0 + n) * K + k0 + k];
        }
        __syncthreads();
        #pragma unroll
        for (int kk = 0; kk < BK; ++kk) {
            float a[TM], b[TN];
            #pragma unroll
            for (int i = 0; i < TM; ++i) a[i] = As[kk][ty * TM + i];
            #pragma unroll
            for (int j = 0; j < TN; ++j) b[j] = Bs[kk][tx * TN + j];
            #pragma unroll
            for (int i = 0; i < TM; ++i)
                #pragma unroll
                for (int j = 0; j < TN; ++j)
                    acc[i][j] = fmaf(a[i], b[j], acc[i][j]);
        }
        __syncthreads();
    }
    #pragma unroll
    for (int i = 0; i < TM; ++i) {
        long long m = row0 + ty * TM + i;
        float* crow = C + m * ldc;
        #pragma unroll
        for (int j = 0; j < TN; ++j) {
            int n = col0 + tx * TN + j;
            float v = acc[i][j];
            if (bias) v += bias[n];
            crow[n] = v;
        }
    }
}

// ---------- fused prologue: Wb cast, Wcat2/bcat2 build (interleaved j*4+comp) ----------
__global__ void prep_kernel(const float* __restrict__ out_W, ushort* __restrict__ Wb,
                            const float* __restrict__ W_ih, const float* __restrict__ W_hh,
                            const float* __restrict__ b_ih, const float* __restrict__ b_hh,
                            float* __restrict__ Wcat2, float* __restrict__ bcat2)
{
    const int stride = gridDim.x * 256;
    const int t0 = blockIdx.x * 256 + threadIdx.x;
    for (int i = t0; i < VOCAB * HSZ / 4; i += stride) {
        const float4 v = ((const float4*)out_W)[i];
        ushort4 o;
        o.x = (ushort)bf16_rne(v.x); o.y = (ushort)bf16_rne(v.y);
        o.z = (ushort)bf16_rne(v.z); o.w = (ushort)bf16_rne(v.w);
        ((ushort4*)Wb)[i] = o;
    }
    for (long long i = t0; i < 2048LL * 576; i += stride) {
        int g = (int)(i / 576), k = (int)(i % 576);
        int j = g >> 2, comp = g & 3;
        float v;
        if (comp == 0)      v = (k < 64) ? W_ih[j * 64 + k]          : W_hh[(long long)j * 512 + k - 64];
        else if (comp == 1) v = (k < 64) ? W_ih[(512 + j) * 64 + k]  : W_hh[(long long)(512 + j) * 512 + k - 64];
        else if (comp == 2) v = (k < 64) ? W_ih[(1024 + j) * 64 + k] : 0.f;
        else                v = (k < 64) ? 0.f                        : W_hh[(long long)(1024 + j) * 512 + k - 64];
        Wcat2[i] = v;
    }
    for (int i = t0; i < 2048; i += stride) {
        int j = i >> 2, comp = i & 3;
        float bv = (comp == 0) ? b_ih[j] + b_hh[j]
                 : (comp == 1) ? b_ih[512 + j] + b_hh[512 + j]
                 : (comp == 2) ? b_ih[1024 + j] : b_hh[1024 + j];
        bcat2[i] = bv;
    }
}

// ---------- G: gcat GEMM + GRU gates. 512 blocks (16 rows x 64 interleaved cols) ----------
template<bool FIRST>
__global__ __launch_bounds__(256) void gru_fused_kernel(
    const float* __restrict__ hprev, float* __restrict__ hnew,
    const float* __restrict__ Wcat2, const float* __restrict__ bcat2,
    const float* __restrict__ ebuf, const float* __restrict__ sos,
    ushort* __restrict__ hbf)
{
    __shared__ __align__(16) char smem[22528];
    const int tid = threadIdx.x;
    const int blk = blockIdx.x;
    const int ty = blk >> 5;            // 16-row batch group (0..15)
    const int tx = blk & 31;            // col group (16 j x 4 comps)
    float* As = (float*)smem;                    // [64][18]
    float* Bs = (float*)(smem + 4608);           // [64][68]
    const int tyt = tid >> 4;           // row 0..15
    const int txt = tid & 15;           // 4 cols
    float acc[4] = {};
    for (int k0 = 0; k0 < 576; k0 += 64) {
        for (int i = tid; i < 16 * 64; i += 256) {
            int m = i >> 6, k = i & 63;
            int kc = k0 + k;
            float v;
            if (kc < 64) v = FIRST ? sos[kc] : ebuf[(long long)(ty * 16 + m) * 64 + kc];
            else         v = hprev[(long long)(ty * 16 + m) * 512 + kc - 64];
            As[k * 18 + m] = v;
        }
        for (int i = tid; i < 64 * 64; i += 256) {
            int n = i >> 6, k = i & 63;
            Bs[k * 68 + n] = Wcat2[(long long)(tx * 64 + n) * 576 + k0 + k];
        }
        __syncthreads();
        #pragma unroll 8
        for (int kk = 0; kk < 64; ++kk) {
            const float a = As[kk * 18 + tyt];
            const float4 b = *(const float4*)&Bs[kk * 68 + txt * 4];
            acc[0] = fmaf(a, b.x, acc[0]);
            acc[1] = fmaf(a, b.y, acc[1]);
            acc[2] = fmaf(a, b.z, acc[2]);
            acc[3] = fmaf(a, b.w, acc[3]);
        }
        __syncthreads();
    }
    float* gt = (float*)smem;            // [16][64] reuse
    #pragma unroll
    for (int j = 0; j < 4; ++j)
        gt[tyt * 64 + txt * 4 + j] = acc[j];
    __syncthreads();
    {
        int row = tid >> 4, jl = tid & 15;     // 256 gate elems: 16 rows x 16 j
        int jg = tx * 16 + jl;
        float gr  = gt[row * 64 + jl * 4 + 0] + bcat2[jg * 4 + 0];
        float gz  = gt[row * 64 + jl * 4 + 1] + bcat2[jg * 4 + 1];
        float gni = gt[row * 64 + jl * 4 + 2] + bcat2[jg * 4 + 2];
        float gnh = gt[row * 64 + jl * 4 + 3] + bcat2[jg * 4 + 3];
        float r = 1.0f / (1.0f + expf(-gr));
        float z = 1.0f / (1.0f + expf(-gz));
        float n = tanhf(gni + r * gnh);
        long long bglob = ty * 16 + row;
        float hold = hprev[bglob * 512 + jg];
        float h = (1.0f - z) * n + z * hold;
        hnew[bglob * 512 + jg] = h;
        hbf[bglob * 512 + jg] = (ushort)bf16_rne(h);
    }
}

// ---------- L: logits MFMA, BM=128 x BN=64, 1000 blocks, XCD-swizzled ----------
__global__ __launch_bounds__(256) void logits_bm128_kernel(
    const ushort* __restrict__ hbf,   // [256][512] bf16
    const ushort* __restrict__ Wb,    // [VOCAB][512] bf16
    const float* __restrict__ out_b,
    float* __restrict__ lbase, float* __restrict__ tmaxv)
{
    __shared__ __align__(16) char As[16384];   // 128 x 64 bf16, XOR-swizzled
    __shared__ __align__(16) char Bs[8192];    // 64 x 64 bf16
    __shared__ float s_mv[128];
    const int tid = threadIdx.x;
    const int lane = tid & 63;
    const int wave = tid >> 6;        // owns rows wave*32..+31
    // bijective XCD swizzle: 1000 jobs = 8 x 125; job pairs share jx
    const int bid = blockIdx.x;
    const int job = (bid & 7) * 125 + (bid >> 3);
    const int jx = job >> 1;
    const int jy = job & 1;
    const int row0 = jy * 128;
    const int col0 = jx * 64;

    f32x4 acc[2][4] = {};
    const int srow = tid >> 3;        // 0..31
    const int sch = tid & 7;

    for (int k0 = 0; k0 < 512; k0 += 64) {
        #pragma unroll
        for (int ra = 0; ra < 4; ++ra) {
            int row = ra * 32 + srow;
            const char* g = (const char*)(hbf + (long long)(row0 + row) * 512 + k0) + ((sch ^ (row & 7)) * 16);
            __builtin_amdgcn_global_load_lds(
                (const __attribute__((address_space(1))) void*)g,
                (__attribute__((address_space(3))) void*)(As + row * 128 + sch * 16), 16, 0, 0);
        }
        #pragma unroll
        for (int rb = 0; rb < 2; ++rb) {
            int row = rb * 32 + srow;
            const char* g = (const char*)(Wb + (long long)(col0 + row) * 512 + k0) + ((sch ^ (row & 7)) * 16);
            __builtin_amdgcn_global_load_lds(
                (const __attribute__((address_space(1))) void*)g,
                (__attribute__((address_space(3))) void*)(Bs + row * 128 + sch * 16), 16, 0, 0);
        }
        __syncthreads();
        #pragma unroll
        for (int k32 = 0; k32 < 64; k32 += 32) {
            bf16x8 af[2], bfr[4];
            #pragma unroll
            for (int f = 0; f < 2; ++f) {
                int rA = wave * 32 + f * 16 + (lane & 15);
                int byteA = (rA * 128 + (k32 + ((lane >> 4) << 3)) * 2) ^ ((rA & 7) << 4);
                af[f] = *(const bf16x8*)&As[byteA];
            }
            #pragma unroll
            for (int j = 0; j < 4; ++j) {
                int rB = j * 16 + (lane & 15);
                int byteB = (rB * 128 + (k32 + ((lane >> 4) << 3)) * 2) ^ ((rB & 7) << 4);
                bfr[j] = *(const bf16x8*)&Bs[byteB];
            }
            #pragma unroll
            for (int f = 0; f < 2; ++f)
                #pragma unroll
                for (int j = 0; j < 4; ++j)
                    acc[f][j] = __builtin_amdgcn_mfma_f32_16x16x32_bf16(af[f], bfr[j], acc[f][j], 0, 0, 0);
        }
        __syncthreads();
    }

    // epilogue: bias + nontemporal store + per-row max over this 64-col tile
    #pragma unroll
    for (int f = 0; f < 2; ++f) {
        #pragma unroll
        for (int q = 0; q < 4; ++q) {
            int r_local = wave * 32 + f * 16 + ((lane >> 4) << 2) + q;
            float* crow = lbase + (long long)(row0 + r_local) * (SLEN * (long long)VOCAB);
            float mv = -INFINITY;
            #pragma unroll
            for (int j = 0; j < 4; ++j) {
                int c = col0 + j * 16 + (lane & 15);
                float v = acc[f][j][q] + out_b[c];
                __builtin_nontemporal_store(v, &crow[c]);
                mv = fmaxf(mv, v);
            }
            #pragma unroll
            for (int m = 1; m < 16; m <<= 1) mv = fmaxf(mv, __shfl_xor(mv, m, 64));
            if ((lane & 15) == 0) s_mv[r_local] = mv;
        }
    }
    __syncthreads();
    if (tid < 128)
        tmaxv[(long long)(row0 + tid) * 512 + jx] = s_mv[tid];
}

// ---------- A: per-row argmax via tile-maxes + exact fp32 refine + embed to ebuf ----------
__global__ __launch_bounds__(256) void argmax_kernel(
    const float* __restrict__ tmaxv, const float* __restrict__ lbase,
    const float* __restrict__ h, const float* __restrict__ out_W,
    const float* __restrict__ out_b, const float* __restrict__ emb,
    float* __restrict__ seq, float* __restrict__ ebuf, int t)
{
    __shared__ float s_red[256];
    __shared__ int s_qt[64];
    __shared__ int s_cand[64];
    __shared__ float s_rv[64];
    __shared__ int s_cnt2[2];
    __shared__ int s_sym;
    const int b = blockIdx.x;
    const int tid = threadIdx.x;
    const int lane = tid & 63, wave = tid >> 6;
    const float* row = lbase + (long long)b * (SLEN * (long long)VOCAB);

    float v0 = tmaxv[(long long)b * 512 + tid];
    float v1 = (tid + 256 < NTILE) ? tmaxv[(long long)b * 512 + 256 + tid] : -INFINITY;
    s_red[tid] = fmaxf(v0, v1); __syncthreads();
    for (int s = 128; s > 0; s >>= 1) {
        if (tid < s) s_red[tid] = fmaxf(s_red[tid], s_red[tid + s]);
        __syncthreads();
    }
    float M = s_red[0];
    if (tid == 0) { s_cnt2[0] = 0; s_cnt2[1] = 0; }
    __syncthreads();
    if (v0 >= M - MARGIN) {
        int s = atomicAdd(&s_cnt2[0], 1);
        if (s < 64) s_qt[s] = tid;
    }
    if (v1 >= M - MARGIN) {
        int s = atomicAdd(&s_cnt2[0], 1);
        if (s < 64) s_qt[s] = tid + 256;
    }
    __syncthreads();
    int nq = min(s_cnt2[0], 64);
    for (int idx = tid; idx < nq * 64; idx += 256) {
        int c = s_qt[idx >> 6] * 64 + (idx & 63);
        if (row[c] >= M - MARGIN) {
            int s = atomicAdd(&s_cnt2[1], 1);
            if (s < 64) s_cand[s] = c;
        }
    }
    __syncthreads();
    int nc = min(s_cnt2[1], 64);
    const float* hrow = h + (long long)b * 512;
    for (int ci = wave; ci < nc; ci += 4) {
        int vv = s_cand[ci];
        const float* wrow = out_W + (long long)vv * 512;
        float s = 0.f;
        for (int k = lane; k < 512; k += 64) s = fmaf(hrow[k], wrow[k], s);
        for (int off = 32; off > 0; off >>= 1) s += __shfl_down(s, off, 64);
        if (lane == 0) s_rv[ci] = s + out_b[vv];
    }
    __syncthreads();
    if (tid == 0) {
        float bv = -INFINITY; int sym = 0x7fffffff;
        for (int ci = 0; ci < nc; ++ci) {
            float xx = s_rv[ci]; int c = s_cand[ci];
            if (xx > bv || (xx == bv && c < sym)) { bv = xx; sym = c; }
        }
        if (sym < 0 || sym >= VOCAB) sym = 0;   // crash-proofing
        seq[b * SLEN + t] = (float)sym;
        s_sym = sym;
    }
    __syncthreads();
    if (tid < EMB) ebuf[(long long)b * EMB + tid] = emb[(long long)s_sym * EMB + tid];
}

extern "C" void kernel_launch(void* const* d_in, const int* in_sizes, int n_in,
                              void* d_out, int out_size, void* d_ws, size_t ws_size,
                              hipStream_t stream) {
    const float* x     = (const float*)d_in[0];
    const float* enc_W = (const float*)d_in[1];
    const float* enc_b = (const float*)d_in[2];
    const float* in_W  = (const float*)d_in[3];
    const float* in_b  = (const float*)d_in[4];
    const float* W_ih  = (const float*)d_in[5];
    const float* W_hh  = (const float*)d_in[6];
    const float* b_ih  = (const float*)d_in[7];
    const float* b_hh  = (const float*)d_in[8];
    const float* out_W = (const float*)d_in[9];
    const float* out_b = (const float*)d_in[10];
    const float* emb   = (const float*)d_in[11];
    const float* sos   = (const float*)d_in[12];

    float* seq    = (float*)d_out;
    float* logits = (float*)d_out + BATCH * SLEN;

    char* p = (char*)d_ws;
    ushort* Wb    = (ushort*)p;  p += (size_t)VOCAB * HSZ * 2;
    float* Wcat2  = (float*)p;   p += (size_t)2048 * 576 * 4;
    float* bcat2  = (float*)p;   p += 2048 * 4;
    float* hA     = (float*)p;   p += (size_t)BATCH * HSZ * 4;
    float* hB     = (float*)p;   p += (size_t)BATCH * HSZ * 4;
    ushort* hbf   = (ushort*)p;  p += (size_t)BATCH * HSZ * 2;
    float* ebuf   = (float*)p;   p += (size_t)BATCH * EMB * 4;
    float* feat   = (float*)p;   p += (size_t)BATCH * DFEAT * 4;
    float* tmaxv  = (float*)p;   p += (size_t)BATCH * 512 * 4;

    // prologue: weights prep + encoder -> input_layer -> h0 (into hA)
    prep_kernel<<<1024, 256, 0, stream>>>(out_W, Wb, W_ih, W_hh, b_ih, b_hh, Wcat2, bcat2);
    gemm_atb<64, 64, 32, 4, 4><<<dim3(DFEAT / 64, BATCH / 64), 256, 0, stream>>>(
        x, enc_W, enc_b, feat, DFEAT, BATCH, DFEAT, DIN);
    gemm_atb<64, 64, 32, 4, 4><<<dim3(HSZ / 64, BATCH / 64), 256, 0, stream>>>(
        feat, in_W, in_b, hA, HSZ, BATCH, HSZ, DFEAT);

    float* hc = hA;
    float* hn = hB;
    for (int t = 0; t < SLEN; ++t) {
        float* lbase = logits + (long long)t * VOCAB;
        if (t == 0) {
            gru_fused_kernel<true><<<512, 256, 0, stream>>>(
                hc, hn, Wcat2, bcat2, ebuf, sos, hbf);
        } else {
            gru_fused_kernel<false><<<512, 256, 0, stream>>>(
                hc, hn, Wcat2, bcat2, ebuf, sos, hbf);
        }
        logits_bm128_kernel<<<1000, 256, 0, stream>>>(hbf, Wb, out_b, lbase, tmaxv);
        argmax_kernel<<<BATCH, 256, 0, stream>>>(
            tmaxv, lbase, hn, out_W, out_b, emb, seq, ebuf, t);
        float* tmp = hc; hc = hn; hn = tmp;
    }
}